// Round 1
// baseline (795.269 us; speedup 1.0000x reference)
//
#include <hip/hip_runtime.h>

#define N_TOK 16384
#define HD 1024
#define ID 1024
#define NE 16
#define CAP 2560
#define NKA 32768   // N_TOK * K assignments

typedef _Float16 f16;
typedef _Float16 f16x4 __attribute__((ext_vector_type(4)));
typedef _Float16 f16x8 __attribute__((ext_vector_type(8)));
typedef float f32x4 __attribute__((ext_vector_type(4)));

__device__ __forceinline__ void async16(f16* lds, const f16* g) {
  __builtin_amdgcn_global_load_lds(
      (const __attribute__((address_space(1))) unsigned int*)g,
      (__attribute__((address_space(3))) unsigned int*)lds, 16, 0, 0);
}

// ---------------- fp32 -> fp16 convert ----------------
__global__ void cvt_kernel(const float* __restrict__ src, f16* __restrict__ dst, int n4) {
  int i = blockIdx.x * blockDim.x + threadIdx.x;
  int stride = gridDim.x * blockDim.x;
  for (; i < n4; i += stride) {
    float4 v = ((const float4*)src)[i];
    f16x4 h = {(f16)v.x, (f16)v.y, (f16)v.z, (f16)v.w};
    ((f16x4*)dst)[i] = h;
  }
}

// ---------------- gating: logits, softmax, top-2, bucket scatter ----------------
__global__ void gate_kernel(const float* __restrict__ x, const float* __restrict__ gw,
                            int* __restrict__ cnt, int* __restrict__ bTok,
                            float* __restrict__ bW, int* __restrict__ bFlat,
                            float* __restrict__ tokW) {
  int t = blockIdx.x;
  int lane = threadIdx.x;  // 64 threads
  const float4* xr = (const float4*)(x + (size_t)t * HD);
  const float4* gr = (const float4*)gw;
  float acc[NE];
#pragma unroll
  for (int e = 0; e < NE; e++) acc[e] = 0.f;
  for (int j = lane; j < HD / 4; j += 64) {
    float4 xv = xr[j];
#pragma unroll
    for (int e = 0; e < NE; e++) {
      float4 gv = gr[e * (HD / 4) + j];
      acc[e] += xv.x * gv.x + xv.y * gv.y + xv.z * gv.z + xv.w * gv.w;
    }
  }
#pragma unroll
  for (int e = 0; e < NE; e++) {
#pragma unroll
    for (int off = 32; off > 0; off >>= 1) acc[e] += __shfl_xor(acc[e], off);
  }
  if (lane == 0) {
    // top-2 on logits (monotonic == top-2 on probs); strict > keeps lowest index (jax tie rule)
    int i0 = 0;
#pragma unroll
    for (int e = 1; e < NE; e++) if (acc[e] > acc[i0]) i0 = e;
    int i1 = (i0 == 0) ? 1 : 0;
#pragma unroll
    for (int e = 0; e < NE; e++) if (e != i0 && acc[e] > acc[i1]) i1 = e;
    float mx = fmaxf(acc[i0], acc[i1]);
    float p0 = __expf(acc[i0] - mx), p1 = __expf(acc[i1] - mx);
    float inv = 1.f / (p0 + p1);
    float w0 = p0 * inv, w1 = p1 * inv;
    int ee[2] = {i0, i1};
    float ww[2] = {w0, w1};
#pragma unroll
    for (int k = 0; k < 2; k++) {
      int e = ee[k];
      int pos = atomicAdd(&cnt[e], 1);
      bTok[e * NKA + pos] = t;
      bW[e * NKA + pos] = ww[k];
      bFlat[e * NKA + pos] = t * 2 + k;
      tokW[t * 2 + k] = ww[k];
    }
  }
}

// ---------------- rank within expert + capacity selection ----------------
__global__ void rank_kernel(const int* __restrict__ cnt, int* __restrict__ mrows,
                            const int* __restrict__ bTok, const float* __restrict__ bW,
                            const int* __restrict__ bFlat, int* __restrict__ rowTok,
                            int* __restrict__ tokSlot) {
  int e = blockIdx.x, tid = threadIdx.x;
  int c = cnt[e];
  int m = c < CAP ? c : CAP;
  if (tid == 0) mrows[e] = m;
  if (c <= CAP) {
    for (int p = tid; p < c; p += blockDim.x) {
      int slot = e * CAP + p;
      rowTok[slot] = bTok[e * NKA + p];
      tokSlot[bFlat[e * NKA + p]] = slot;
    }
  } else {
    for (int p = tid; p < c; p += blockDim.x) {
      float wp = bW[e * NKA + p];
      int fp = bFlat[e * NKA + p];
      int rank = 0;
      for (int q = 0; q < c; q++) {
        float wq = bW[e * NKA + q];
        rank += (wq > wp) || (wq == wp && bFlat[e * NKA + q] < fp);
      }
      if (rank < CAP) {
        int slot = e * CAP + rank;
        rowTok[slot] = bTok[e * NKA + p];
        tokSlot[fp] = slot;
      } else {
        tokSlot[fp] = -1;
      }
    }
  }
}

// ---------------- GEMM1: gathered X @ {wg,wu}^T, fused silu*u -> GU fp16 ----------------
// tile: BM=128 (slots) x BN=64 (i) x BK=32 (h); 4 waves (2x2), per wave 64x32 of both g,u
__global__ __launch_bounds__(256, 2) void gemm1_kernel(
    const f16* __restrict__ Xh, const f16* __restrict__ WGh, const f16* __restrict__ WUh,
    const int* __restrict__ rowTok, const int* __restrict__ mrows, f16* __restrict__ GU) {
  __shared__ __align__(16) f16 As[2][128 * 32];
  __shared__ __align__(16) f16 Bg[2][64 * 32];
  __shared__ __align__(16) f16 Bu[2][64 * 32];

  int bid = blockIdx.x;
  int e = bid / (20 * 16);
  int r2 = bid % (20 * 16);
  int rb = r2 / 16, cb = r2 % 16;
  int me = mrows[e];
  if (rb * 128 >= me) return;

  int tid = threadIdx.x;
  int wave = tid >> 6, lane = tid & 63;
  int wr = wave >> 1, wc = wave & 1;

  // A staging: 128x32 halves = 2 x (256 lanes x 16B); gather rows via rowTok, pre-swizzled source
  const f16* aSrc[2];
  int aOff[2];
#pragma unroll
  for (int j = 0; j < 2; j++) {
    int o = j * 256 + tid;
    int row = o >> 2, ch = o & 3;
    int rg = rb * 128 + row;
    int tok = (rg < me) ? rowTok[e * CAP + rg] : 0;
    aSrc[j] = Xh + (size_t)tok * HD + ((ch ^ (row & 3)) * 8);
    aOff[j] = (j * 256 + wave * 64) * 8;
  }
  // B staging: 64x32 halves each = 256 lanes x 16B
  int rowB = tid >> 2, chB = tid & 3;
  size_t wOff = (size_t)e * ID * HD + (size_t)(cb * 64 + rowB) * HD + ((chB ^ (rowB & 3)) * 8);
  const f16* gSrc = WGh + wOff;
  const f16* uSrc = WUh + wOff;
  int bOff = wave * 512;

  async16(&As[0][aOff[0]], aSrc[0]);
  async16(&As[0][aOff[1]], aSrc[1]);
  async16(&Bg[0][bOff], gSrc);
  async16(&Bu[0][bOff], uSrc);
  __syncthreads();

  f32x4 accg[4][2] = {};
  f32x4 accu[4][2] = {};

  int cur = 0;
  for (int kt = 0; kt < 32; kt++) {
    if (kt + 1 < 32) {
      int kh = (kt + 1) * 32;
      async16(&As[cur ^ 1][aOff[0]], aSrc[0] + kh);
      async16(&As[cur ^ 1][aOff[1]], aSrc[1] + kh);
      async16(&Bg[cur ^ 1][bOff], gSrc + kh);
      async16(&Bu[cur ^ 1][bOff], uSrc + kh);
    }
    f16x8 a[4], bg[2], bu[2];
#pragma unroll
    for (int m = 0; m < 4; m++) {
      int row = wr * 64 + m * 16 + (lane & 15);
      int kc = (lane >> 4) ^ (row & 3);
      a[m] = *(const f16x8*)&As[cur][row * 32 + kc * 8];
    }
#pragma unroll
    for (int n = 0; n < 2; n++) {
      int row = wc * 32 + n * 16 + (lane & 15);
      int kc = (lane >> 4) ^ (row & 3);
      bg[n] = *(const f16x8*)&Bg[cur][row * 32 + kc * 8];
      bu[n] = *(const f16x8*)&Bu[cur][row * 32 + kc * 8];
    }
#pragma unroll
    for (int m = 0; m < 4; m++)
#pragma unroll
      for (int n = 0; n < 2; n++) {
        accg[m][n] = __builtin_amdgcn_mfma_f32_16x16x32_f16(a[m], bg[n], accg[m][n], 0, 0, 0);
        accu[m][n] = __builtin_amdgcn_mfma_f32_16x16x32_f16(a[m], bu[n], accu[m][n], 0, 0, 0);
      }
    __syncthreads();
    cur ^= 1;
  }

  int rbase = e * CAP + rb * 128 + wr * 64;
  int cbase = cb * 64 + wc * 32;
#pragma unroll
  for (int m = 0; m < 4; m++)
#pragma unroll
    for (int n = 0; n < 2; n++)
#pragma unroll
      for (int r = 0; r < 4; r++) {
        int row = rbase + m * 16 + (lane >> 4) * 4 + r;
        int col = cbase + n * 16 + (lane & 15);
        float g = accg[m][n][r];
        float u = accu[m][n][r];
        float s = g / (1.f + __expf(-g));
        GU[(size_t)row * ID + col] = (f16)(s * u);
      }
}

// ---------------- GEMM2: GU @ wd^T -> OE fp16 ----------------
// tile: BM=128 x BN=128 x BK=32; 4 waves (2x2), per wave 64x64
__global__ __launch_bounds__(256, 2) void gemm2_kernel(
    const f16* __restrict__ GU, const f16* __restrict__ WDh,
    const int* __restrict__ mrows, f16* __restrict__ OE) {
  __shared__ __align__(16) f16 As[2][128 * 32];
  __shared__ __align__(16) f16 Bs[2][128 * 32];

  int bid = blockIdx.x;
  int e = bid / (20 * 8);
  int r2 = bid % (20 * 8);
  int rb = r2 / 8, cb = r2 % 8;
  if (rb * 128 >= mrows[e]) return;

  int tid = threadIdx.x;
  int wave = tid >> 6, lane = tid & 63;
  int wr = wave >> 1, wc = wave & 1;

  const f16* aSrc[2];
  const f16* bSrc[2];
  int sOff[2];
#pragma unroll
  for (int j = 0; j < 2; j++) {
    int o = j * 256 + tid;
    int row = o >> 2, ch = o & 3;
    aSrc[j] = GU + (size_t)(e * CAP + rb * 128 + row) * ID + ((ch ^ (row & 3)) * 8);
    bSrc[j] = WDh + (size_t)e * HD * ID + (size_t)(cb * 128 + row) * ID + ((ch ^ (row & 3)) * 8);
    sOff[j] = (j * 256 + wave * 64) * 8;
  }

  async16(&As[0][sOff[0]], aSrc[0]);
  async16(&As[0][sOff[1]], aSrc[1]);
  async16(&Bs[0][sOff[0]], bSrc[0]);
  async16(&Bs[0][sOff[1]], bSrc[1]);
  __syncthreads();

  f32x4 acc[4][4] = {};

  int cur = 0;
  for (int kt = 0; kt < 32; kt++) {
    if (kt + 1 < 32) {
      int kh = (kt + 1) * 32;
      async16(&As[cur ^ 1][sOff[0]], aSrc[0] + kh);
      async16(&As[cur ^ 1][sOff[1]], aSrc[1] + kh);
      async16(&Bs[cur ^ 1][sOff[0]], bSrc[0] + kh);
      async16(&Bs[cur ^ 1][sOff[1]], bSrc[1] + kh);
    }
    f16x8 a[4], b[4];
#pragma unroll
    for (int m = 0; m < 4; m++) {
      int row = wr * 64 + m * 16 + (lane & 15);
      int kc = (lane >> 4) ^ (row & 3);
      a[m] = *(const f16x8*)&As[cur][row * 32 + kc * 8];
    }
#pragma unroll
    for (int n = 0; n < 4; n++) {
      int row = wc * 64 + n * 16 + (lane & 15);
      int kc = (lane >> 4) ^ (row & 3);
      b[n] = *(const f16x8*)&Bs[cur][row * 32 + kc * 8];
    }
#pragma unroll
    for (int m = 0; m < 4; m++)
#pragma unroll
      for (int n = 0; n < 4; n++)
        acc[m][n] = __builtin_amdgcn_mfma_f32_16x16x32_f16(a[m], b[n], acc[m][n], 0, 0, 0);
    __syncthreads();
    cur ^= 1;
  }

  int rbase = e * CAP + rb * 128 + wr * 64;
  int cbase = cb * 128 + wc * 64;
#pragma unroll
  for (int m = 0; m < 4; m++)
#pragma unroll
    for (int n = 0; n < 4; n++)
#pragma unroll
      for (int r = 0; r < 4; r++) {
        int row = rbase + m * 16 + (lane >> 4) * 4 + r;
        int col = cbase + n * 16 + (lane & 15);
        OE[(size_t)row * HD + col] = (f16)acc[m][n][r];
      }
}

// ---------------- combine: out[t] = sum_k w_k * OE[slot_k] ----------------
__global__ void combine_kernel(const f16* __restrict__ OE, const int* __restrict__ tokSlot,
                               const float* __restrict__ tokW, float* __restrict__ out) {
  int t = blockIdx.x, tid = threadIdx.x;
  int s0 = tokSlot[t * 2], s1 = tokSlot[t * 2 + 1];
  float w0 = tokW[t * 2], w1 = tokW[t * 2 + 1];
  int c = tid * 4;
  float4 o = {0.f, 0.f, 0.f, 0.f};
  if (s0 >= 0) {
    f16x4 v = *(const f16x4*)&OE[(size_t)s0 * HD + c];
    o.x += w0 * (float)v[0]; o.y += w0 * (float)v[1];
    o.z += w0 * (float)v[2]; o.w += w0 * (float)v[3];
  }
  if (s1 >= 0) {
    f16x4 v = *(const f16x4*)&OE[(size_t)s1 * HD + c];
    o.x += w1 * (float)v[0]; o.y += w1 * (float)v[1];
    o.z += w1 * (float)v[2]; o.w += w1 * (float)v[3];
  }
  *(float4*)&out[(size_t)t * HD + c] = o;
  if (t == 0 && tid == 0) out[(size_t)N_TOK * HD] = 0.f;  // aux_loss
}

extern "C" void kernel_launch(void* const* d_in, const int* in_sizes, int n_in,
                              void* d_out, int out_size, void* d_ws, size_t ws_size,
                              hipStream_t stream) {
  (void)in_sizes; (void)n_in; (void)out_size; (void)ws_size;
  const float* x  = (const float*)d_in[0];
  const float* gw = (const float*)d_in[1];
  const float* wg = (const float*)d_in[2];
  const float* wu = (const float*)d_in[3];
  const float* wd = (const float*)d_in[4];
  float* out = (float*)d_out;

  char* ws = (char*)d_ws;
  f16* Xh  = (f16*)ws;                          // 32 MB
  f16* WGh = (f16*)(ws + 33554432ll);           // 32 MB
  f16* WUh = (f16*)(ws + 67108864ll);           // 32 MB
  f16* WDh = (f16*)(ws + 100663296ll);          // 32 MB
  f16* GU  = (f16*)(ws + 134217728ll);          // 80 MB
  f16* OE  = (f16*)ws;                          // aliases Xh/WGh/part-WUh (dead by GEMM2)
  char* rt = ws + 218103808ll;
  int*   cnt     = (int*)rt;                    // 64 B
  int*   mrows   = (int*)(rt + 64);             // 64 B
  int*   rowTok  = (int*)(rt + 128);            // 160 KB
  int*   tokSlot = (int*)(rt + 128 + 163840);   // 128 KB
  float* tokW    = (float*)(rt + 128 + 163840 + 131072);
  char*  rb      = rt + 128 + 163840 + 131072 + 131072;
  int*   bTok  = (int*)rb;                      // 2 MB
  float* bW    = (float*)(rb + 2097152);        // 2 MB
  int*   bFlat = (int*)(rb + 4194304);          // 2 MB

  hipMemsetAsync(cnt, 0, 64, stream);
  cvt_kernel<<<4096, 256, 0, stream>>>(x,  Xh,  N_TOK * HD / 4);
  cvt_kernel<<<4096, 256, 0, stream>>>(wg, WGh, NE * ID * HD / 4);
  cvt_kernel<<<4096, 256, 0, stream>>>(wu, WUh, NE * ID * HD / 4);
  cvt_kernel<<<4096, 256, 0, stream>>>(wd, WDh, NE * HD * ID / 4);
  gate_kernel<<<N_TOK, 64, 0, stream>>>(x, gw, cnt, bTok, bW, bFlat, tokW);
  rank_kernel<<<NE, 256, 0, stream>>>(cnt, mrows, bTok, bW, bFlat, rowTok, tokSlot);
  gemm1_kernel<<<NE * 20 * 16, 256, 0, stream>>>(Xh, WGh, WUh, rowTok, mrows, GU);
  gemm2_kernel<<<NE * 20 * 8, 256, 0, stream>>>(GU, WDh, mrows, OE);
  combine_kernel<<<N_TOK, 256, 0, stream>>>(OE, tokSlot, tokW, out);
}

// Round 2
// 484.066 us; speedup vs baseline: 1.6429x; 1.6429x over previous
//
#include <hip/hip_runtime.h>

#define N_TOK 16384
#define HD 1024
#define ID 1024
#define NE 16
#define CAP 2560
#define NKA 32768   // N_TOK * K assignments

typedef _Float16 f16;
typedef _Float16 f16x4 __attribute__((ext_vector_type(4)));
typedef _Float16 f16x8 __attribute__((ext_vector_type(8)));
typedef float f32x4 __attribute__((ext_vector_type(4)));

__device__ __forceinline__ void async16(f16* lds, const f16* g) {
  __builtin_amdgcn_global_load_lds(
      (const __attribute__((address_space(1))) unsigned int*)g,
      (__attribute__((address_space(3))) unsigned int*)lds, 16, 0, 0);
}

// ---------------- fp32 -> fp16 convert ----------------
__global__ void cvt_kernel(const float* __restrict__ src, f16* __restrict__ dst, int n4) {
  int i = blockIdx.x * blockDim.x + threadIdx.x;
  int stride = gridDim.x * blockDim.x;
  for (; i < n4; i += stride) {
    float4 v = ((const float4*)src)[i];
    f16x4 h = {(f16)v.x, (f16)v.y, (f16)v.z, (f16)v.w};
    ((f16x4*)dst)[i] = h;
  }
}

// ---------------- gating: logits, softmax, top-2 (no atomics) ----------------
__global__ void gate_kernel(const float* __restrict__ x, const float* __restrict__ gw,
                            int* __restrict__ tokE, float* __restrict__ tokW) {
  int t = blockIdx.x * 4 + (threadIdx.x >> 6);
  int lane = threadIdx.x & 63;
  const float4* xr = (const float4*)(x + (size_t)t * HD);
  const float4* gr = (const float4*)gw;
  float acc[NE];
#pragma unroll
  for (int e = 0; e < NE; e++) acc[e] = 0.f;
  for (int j = lane; j < HD / 4; j += 64) {
    float4 xv = xr[j];
#pragma unroll
    for (int e = 0; e < NE; e++) {
      float4 gv = gr[e * (HD / 4) + j];
      acc[e] += xv.x * gv.x + xv.y * gv.y + xv.z * gv.z + xv.w * gv.w;
    }
  }
#pragma unroll
  for (int e = 0; e < NE; e++) {
#pragma unroll
    for (int off = 32; off > 0; off >>= 1) acc[e] += __shfl_xor(acc[e], off);
  }
  if (lane == 0) {
    // top-2 on logits (monotonic == top-2 on probs); strict > keeps lowest index (jax tie rule)
    int i0 = 0;
#pragma unroll
    for (int e = 1; e < NE; e++) if (acc[e] > acc[i0]) i0 = e;
    int i1 = (i0 == 0) ? 1 : 0;
#pragma unroll
    for (int e = 0; e < NE; e++) if (e != i0 && acc[e] > acc[i1]) i1 = e;
    float mx = fmaxf(acc[i0], acc[i1]);
    float p0 = __expf(acc[i0] - mx), p1 = __expf(acc[i1] - mx);
    float inv = 1.f / (p0 + p1);
    tokE[t * 2] = i0;
    tokE[t * 2 + 1] = i1;
    tokW[t * 2] = p0 * inv;
    tokW[t * 2 + 1] = p1 * inv;
  }
}

// ---------------- bucket: ballot-compaction per expert (deterministic, atomic-free) ----------------
__global__ __launch_bounds__(1024) void bucket_kernel(
    const int* __restrict__ tokE, const float* __restrict__ tokW,
    int* __restrict__ cnt, int* __restrict__ bTok, float* __restrict__ bW,
    int* __restrict__ bFlat) {
  int e = blockIdx.x;
  int tid = threadIdx.x;  // 1024 = 16 waves
  int wid = tid >> 6, lane = tid & 63;
  __shared__ int wsum[16];
  __shared__ int wbase[16];
  __shared__ int chunkTotal;
  int total = 0;
  for (int c = 0; c < NKA; c += 1024) {
    int a = c + tid;
    bool pred = (tokE[a] == e);
    unsigned long long mask = __ballot(pred);
    int myrank = __popcll(mask & ((1ull << lane) - 1ull));
    if (lane == 0) wsum[wid] = __popcll(mask);
    __syncthreads();
    if (tid == 0) {
      int s = 0;
#pragma unroll
      for (int w = 0; w < 16; w++) { wbase[w] = s; s += wsum[w]; }
      chunkTotal = s;
    }
    __syncthreads();
    if (pred) {
      int pos = total + wbase[wid] + myrank;
      bTok[e * NKA + pos] = a >> 1;
      bW[e * NKA + pos] = tokW[a];
      bFlat[e * NKA + pos] = a;
    }
    total += chunkTotal;
    __syncthreads();
  }
  if (tid == 0) cnt[e] = total;
}

// ---------------- rank within expert + capacity selection ----------------
__global__ void rank_kernel(const int* __restrict__ cnt, int* __restrict__ mrows,
                            const int* __restrict__ bTok, const float* __restrict__ bW,
                            const int* __restrict__ bFlat, int* __restrict__ rowTok,
                            int* __restrict__ tokSlot) {
  int e = blockIdx.x, tid = threadIdx.x;
  int c = cnt[e];
  int m = c < CAP ? c : CAP;
  if (tid == 0) mrows[e] = m;
  if (c <= CAP) {
    for (int p = tid; p < c; p += blockDim.x) {
      int slot = e * CAP + p;
      rowTok[slot] = bTok[e * NKA + p];
      tokSlot[bFlat[e * NKA + p]] = slot;
    }
  } else {
    for (int p = tid; p < c; p += blockDim.x) {
      float wp = bW[e * NKA + p];
      int fp = bFlat[e * NKA + p];
      int rank = 0;
      for (int q = 0; q < c; q++) {
        float wq = bW[e * NKA + q];
        rank += (wq > wp) || (wq == wp && bFlat[e * NKA + q] < fp);
      }
      if (rank < CAP) {
        int slot = e * CAP + rank;
        rowTok[slot] = bTok[e * NKA + p];
        tokSlot[fp] = slot;
      } else {
        tokSlot[fp] = -1;
      }
    }
  }
}

// ---------------- GEMM1: gathered X @ {wg,wu}^T, fused silu*u -> GU fp16 ----------------
// tile: BM=128 (slots) x BN=64 (i) x BK=32 (h); 4 waves (2x2), per wave 64x32 of both g,u
__global__ __launch_bounds__(256, 2) void gemm1_kernel(
    const f16* __restrict__ Xh, const f16* __restrict__ WGh, const f16* __restrict__ WUh,
    const int* __restrict__ rowTok, const int* __restrict__ mrows, f16* __restrict__ GU) {
  __shared__ __align__(16) f16 As[2][128 * 32];
  __shared__ __align__(16) f16 Bg[2][64 * 32];
  __shared__ __align__(16) f16 Bu[2][64 * 32];

  int bid = blockIdx.x;
  int e = bid / (20 * 16);
  int r2 = bid % (20 * 16);
  int rb = r2 / 16, cb = r2 % 16;
  int me = mrows[e];
  if (rb * 128 >= me) return;

  int tid = threadIdx.x;
  int wave = tid >> 6, lane = tid & 63;
  int wr = wave >> 1, wc = wave & 1;

  // A staging: 128x32 halves = 2 x (256 lanes x 16B); gather rows via rowTok, pre-swizzled source
  const f16* aSrc[2];
  int aOff[2];
#pragma unroll
  for (int j = 0; j < 2; j++) {
    int o = j * 256 + tid;
    int row = o >> 2, ch = o & 3;
    int rg = rb * 128 + row;
    int tok = (rg < me) ? rowTok[e * CAP + rg] : 0;
    aSrc[j] = Xh + (size_t)tok * HD + ((ch ^ (row & 3)) * 8);
    aOff[j] = (j * 256 + wave * 64) * 8;
  }
  // B staging: 64x32 halves each = 256 lanes x 16B
  int rowB = tid >> 2, chB = tid & 3;
  size_t wOff = (size_t)e * ID * HD + (size_t)(cb * 64 + rowB) * HD + ((chB ^ (rowB & 3)) * 8);
  const f16* gSrc = WGh + wOff;
  const f16* uSrc = WUh + wOff;
  int bOff = wave * 512;

  async16(&As[0][aOff[0]], aSrc[0]);
  async16(&As[0][aOff[1]], aSrc[1]);
  async16(&Bg[0][bOff], gSrc);
  async16(&Bu[0][bOff], uSrc);
  __syncthreads();

  f32x4 accg[4][2] = {};
  f32x4 accu[4][2] = {};

  int cur = 0;
  for (int kt = 0; kt < 32; kt++) {
    if (kt + 1 < 32) {
      int kh = (kt + 1) * 32;
      async16(&As[cur ^ 1][aOff[0]], aSrc[0] + kh);
      async16(&As[cur ^ 1][aOff[1]], aSrc[1] + kh);
      async16(&Bg[cur ^ 1][bOff], gSrc + kh);
      async16(&Bu[cur ^ 1][bOff], uSrc + kh);
    }
    f16x8 a[4], bg[2], bu[2];
#pragma unroll
    for (int m = 0; m < 4; m++) {
      int row = wr * 64 + m * 16 + (lane & 15);
      int kc = (lane >> 4) ^ (row & 3);
      a[m] = *(const f16x8*)&As[cur][row * 32 + kc * 8];
    }
#pragma unroll
    for (int n = 0; n < 2; n++) {
      int row = wc * 32 + n * 16 + (lane & 15);
      int kc = (lane >> 4) ^ (row & 3);
      bg[n] = *(const f16x8*)&Bg[cur][row * 32 + kc * 8];
      bu[n] = *(const f16x8*)&Bu[cur][row * 32 + kc * 8];
    }
#pragma unroll
    for (int m = 0; m < 4; m++)
#pragma unroll
      for (int n = 0; n < 2; n++) {
        accg[m][n] = __builtin_amdgcn_mfma_f32_16x16x32_f16(a[m], bg[n], accg[m][n], 0, 0, 0);
        accu[m][n] = __builtin_amdgcn_mfma_f32_16x16x32_f16(a[m], bu[n], accu[m][n], 0, 0, 0);
      }
    __syncthreads();
    cur ^= 1;
  }

  int rbase = e * CAP + rb * 128 + wr * 64;
  int cbase = cb * 64 + wc * 32;
#pragma unroll
  for (int m = 0; m < 4; m++)
#pragma unroll
    for (int n = 0; n < 2; n++)
#pragma unroll
      for (int r = 0; r < 4; r++) {
        int row = rbase + m * 16 + (lane >> 4) * 4 + r;
        int col = cbase + n * 16 + (lane & 15);
        float g = accg[m][n][r];
        float u = accu[m][n][r];
        float s = g / (1.f + __expf(-g));
        GU[(size_t)row * ID + col] = (f16)(s * u);
      }
}

// ---------------- GEMM2: GU @ wd^T -> OE fp16 ----------------
// tile: BM=128 x BN=128 x BK=32; 4 waves (2x2), per wave 64x64
__global__ __launch_bounds__(256, 2) void gemm2_kernel(
    const f16* __restrict__ GU, const f16* __restrict__ WDh,
    const int* __restrict__ mrows, f16* __restrict__ OE) {
  __shared__ __align__(16) f16 As[2][128 * 32];
  __shared__ __align__(16) f16 Bs[2][128 * 32];

  int bid = blockIdx.x;
  int e = bid / (20 * 8);
  int r2 = bid % (20 * 8);
  int rb = r2 / 8, cb = r2 % 8;
  if (rb * 128 >= mrows[e]) return;

  int tid = threadIdx.x;
  int wave = tid >> 6, lane = tid & 63;
  int wr = wave >> 1, wc = wave & 1;

  const f16* aSrc[2];
  const f16* bSrc[2];
  int sOff[2];
#pragma unroll
  for (int j = 0; j < 2; j++) {
    int o = j * 256 + tid;
    int row = o >> 2, ch = o & 3;
    aSrc[j] = GU + (size_t)(e * CAP + rb * 128 + row) * ID + ((ch ^ (row & 3)) * 8);
    bSrc[j] = WDh + (size_t)e * HD * ID + (size_t)(cb * 128 + row) * ID + ((ch ^ (row & 3)) * 8);
    sOff[j] = (j * 256 + wave * 64) * 8;
  }

  async16(&As[0][sOff[0]], aSrc[0]);
  async16(&As[0][sOff[1]], aSrc[1]);
  async16(&Bs[0][sOff[0]], bSrc[0]);
  async16(&Bs[0][sOff[1]], bSrc[1]);
  __syncthreads();

  f32x4 acc[4][4] = {};

  int cur = 0;
  for (int kt = 0; kt < 32; kt++) {
    if (kt + 1 < 32) {
      int kh = (kt + 1) * 32;
      async16(&As[cur ^ 1][sOff[0]], aSrc[0] + kh);
      async16(&As[cur ^ 1][sOff[1]], aSrc[1] + kh);
      async16(&Bs[cur ^ 1][sOff[0]], bSrc[0] + kh);
      async16(&Bs[cur ^ 1][sOff[1]], bSrc[1] + kh);
    }
    f16x8 a[4], b[4];
#pragma unroll
    for (int m = 0; m < 4; m++) {
      int row = wr * 64 + m * 16 + (lane & 15);
      int kc = (lane >> 4) ^ (row & 3);
      a[m] = *(const f16x8*)&As[cur][row * 32 + kc * 8];
    }
#pragma unroll
    for (int n = 0; n < 4; n++) {
      int row = wc * 64 + n * 16 + (lane & 15);
      int kc = (lane >> 4) ^ (row & 3);
      b[n] = *(const f16x8*)&Bs[cur][row * 32 + kc * 8];
    }
#pragma unroll
    for (int m = 0; m < 4; m++)
#pragma unroll
      for (int n = 0; n < 4; n++)
        acc[m][n] = __builtin_amdgcn_mfma_f32_16x16x32_f16(a[m], b[n], acc[m][n], 0, 0, 0);
    __syncthreads();
    cur ^= 1;
  }

  int rbase = e * CAP + rb * 128 + wr * 64;
  int cbase = cb * 128 + wc * 64;
#pragma unroll
  for (int m = 0; m < 4; m++)
#pragma unroll
    for (int n = 0; n < 4; n++)
#pragma unroll
      for (int r = 0; r < 4; r++) {
        int row = rbase + m * 16 + (lane >> 4) * 4 + r;
        int col = cbase + n * 16 + (lane & 15);
        OE[(size_t)row * HD + col] = (f16)acc[m][n][r];
      }
}

// ---------------- combine: out[t] = sum_k w_k * OE[slot_k] ----------------
__global__ void combine_kernel(const f16* __restrict__ OE, const int* __restrict__ tokSlot,
                               const float* __restrict__ tokW, float* __restrict__ out) {
  int t = blockIdx.x, tid = threadIdx.x;
  int s0 = tokSlot[t * 2], s1 = tokSlot[t * 2 + 1];
  float w0 = tokW[t * 2], w1 = tokW[t * 2 + 1];
  int c = tid * 4;
  float4 o = {0.f, 0.f, 0.f, 0.f};
  if (s0 >= 0) {
    f16x4 v = *(const f16x4*)&OE[(size_t)s0 * HD + c];
    o.x += w0 * (float)v[0]; o.y += w0 * (float)v[1];
    o.z += w0 * (float)v[2]; o.w += w0 * (float)v[3];
  }
  if (s1 >= 0) {
    f16x4 v = *(const f16x4*)&OE[(size_t)s1 * HD + c];
    o.x += w1 * (float)v[0]; o.y += w1 * (float)v[1];
    o.z += w1 * (float)v[2]; o.w += w1 * (float)v[3];
  }
  *(float4*)&out[(size_t)t * HD + c] = o;
  if (t == 0 && tid == 0) out[(size_t)N_TOK * HD] = 0.f;  // aux_loss
}

extern "C" void kernel_launch(void* const* d_in, const int* in_sizes, int n_in,
                              void* d_out, int out_size, void* d_ws, size_t ws_size,
                              hipStream_t stream) {
  (void)in_sizes; (void)n_in; (void)out_size; (void)ws_size;
  const float* x  = (const float*)d_in[0];
  const float* gw = (const float*)d_in[1];
  const float* wg = (const float*)d_in[2];
  const float* wu = (const float*)d_in[3];
  const float* wd = (const float*)d_in[4];
  float* out = (float*)d_out;

  char* ws = (char*)d_ws;
  f16* Xh  = (f16*)ws;                          // 32 MB
  f16* WGh = (f16*)(ws + 33554432ll);           // 32 MB
  f16* WUh = (f16*)(ws + 67108864ll);           // 32 MB
  f16* WDh = (f16*)(ws + 100663296ll);          // 32 MB
  f16* GU  = (f16*)(ws + 134217728ll);          // 80 MB
  f16* OE  = (f16*)ws;                          // aliases Xh/WGh/part-WUh (dead by GEMM2)
  char* rt = ws + 218103808ll;
  int*   cnt     = (int*)rt;                    // 64 B
  int*   mrows   = (int*)(rt + 64);             // 64 B
  int*   rowTok  = (int*)(rt + 128);            // 160 KB
  int*   tokSlot = (int*)(rt + 128 + 163840);   // 128 KB
  float* tokW    = (float*)(rt + 128 + 163840 + 131072);
  char*  rb      = rt + 128 + 163840 + 131072 + 131072;
  int*   bTok  = (int*)rb;                      // 2 MB
  float* bW    = (float*)(rb + 2097152);        // 2 MB
  int*   bFlat = (int*)(rb + 4194304);          // 2 MB
  int*   tokE  = (int*)(rb + 6291456);          // 128 KB

  cvt_kernel<<<4096, 256, 0, stream>>>(x,  Xh,  N_TOK * HD / 4);
  cvt_kernel<<<4096, 256, 0, stream>>>(wg, WGh, NE * ID * HD / 4);
  cvt_kernel<<<4096, 256, 0, stream>>>(wu, WUh, NE * ID * HD / 4);
  cvt_kernel<<<4096, 256, 0, stream>>>(wd, WDh, NE * HD * ID / 4);
  gate_kernel<<<N_TOK / 4, 256, 0, stream>>>(x, gw, tokE, tokW);
  bucket_kernel<<<NE, 1024, 0, stream>>>(tokE, tokW, cnt, bTok, bW, bFlat);
  rank_kernel<<<NE, 256, 0, stream>>>(cnt, mrows, bTok, bW, bFlat, rowTok, tokSlot);
  gemm1_kernel<<<NE * 20 * 16, 256, 0, stream>>>(Xh, WGh, WUh, rowTok, mrows, GU);
  gemm2_kernel<<<NE * 20 * 8, 256, 0, stream>>>(GU, WDh, mrows, OE);
  combine_kernel<<<N_TOK, 256, 0, stream>>>(OE, tokSlot, tokW, out);
}

// Round 3
// 463.249 us; speedup vs baseline: 1.7167x; 1.0449x over previous
//
#include <hip/hip_runtime.h>

#define N_TOK 16384
#define HD 1024
#define ID 1024
#define NE 16
#define CAP 2560
#define NKA 32768   // N_TOK * K assignments

typedef _Float16 f16;
typedef _Float16 f16x4 __attribute__((ext_vector_type(4)));
typedef _Float16 f16x8 __attribute__((ext_vector_type(8)));
typedef float f32x4 __attribute__((ext_vector_type(4)));

__device__ __forceinline__ void async16(f16* lds, const f16* g) {
  __builtin_amdgcn_global_load_lds(
      (const __attribute__((address_space(1))) unsigned int*)g,
      (__attribute__((address_space(3))) unsigned int*)lds, 16, 0, 0);
}

// ---------------- fp32 -> fp16 convert ----------------
__global__ void cvt_kernel(const float* __restrict__ src, f16* __restrict__ dst, int n4) {
  int i = blockIdx.x * blockDim.x + threadIdx.x;
  int stride = gridDim.x * blockDim.x;
  for (; i < n4; i += stride) {
    float4 v = ((const float4*)src)[i];
    f16x4 h = {(f16)v.x, (f16)v.y, (f16)v.z, (f16)v.w};
    ((f16x4*)dst)[i] = h;
  }
}

// ---------------- gating: logits, softmax, top-2 (no atomics) ----------------
__global__ void gate_kernel(const float* __restrict__ x, const float* __restrict__ gw,
                            int* __restrict__ tokE, float* __restrict__ tokW) {
  int t = blockIdx.x * 4 + (threadIdx.x >> 6);
  int lane = threadIdx.x & 63;
  const float4* xr = (const float4*)(x + (size_t)t * HD);
  const float4* gr = (const float4*)gw;
  float acc[NE];
#pragma unroll
  for (int e = 0; e < NE; e++) acc[e] = 0.f;
  for (int j = lane; j < HD / 4; j += 64) {
    float4 xv = xr[j];
#pragma unroll
    for (int e = 0; e < NE; e++) {
      float4 gv = gr[e * (HD / 4) + j];
      acc[e] += xv.x * gv.x + xv.y * gv.y + xv.z * gv.z + xv.w * gv.w;
    }
  }
#pragma unroll
  for (int e = 0; e < NE; e++) {
#pragma unroll
    for (int off = 32; off > 0; off >>= 1) acc[e] += __shfl_xor(acc[e], off);
  }
  if (lane == 0) {
    int i0 = 0;
#pragma unroll
    for (int e = 1; e < NE; e++) if (acc[e] > acc[i0]) i0 = e;
    int i1 = (i0 == 0) ? 1 : 0;
#pragma unroll
    for (int e = 0; e < NE; e++) if (e != i0 && acc[e] > acc[i1]) i1 = e;
    float mx = fmaxf(acc[i0], acc[i1]);
    float p0 = __expf(acc[i0] - mx), p1 = __expf(acc[i1] - mx);
    float inv = 1.f / (p0 + p1);
    tokE[t * 2] = i0;
    tokE[t * 2 + 1] = i1;
    tokW[t * 2] = p0 * inv;
    tokW[t * 2 + 1] = p1 * inv;
  }
}

// ---------------- bucket: ballot-compaction per expert (deterministic, atomic-free) ----------------
__global__ __launch_bounds__(1024) void bucket_kernel(
    const int* __restrict__ tokE, const float* __restrict__ tokW,
    int* __restrict__ cnt, int* __restrict__ bTok, float* __restrict__ bW,
    int* __restrict__ bFlat) {
  int e = blockIdx.x;
  int tid = threadIdx.x;  // 1024 = 16 waves
  int wid = tid >> 6, lane = tid & 63;
  __shared__ int wsum[16];
  __shared__ int wbase[16];
  __shared__ int chunkTotal;
  int total = 0;
  for (int c = 0; c < NKA; c += 1024) {
    int a = c + tid;
    bool pred = (tokE[a] == e);
    unsigned long long mask = __ballot(pred);
    int myrank = __popcll(mask & ((1ull << lane) - 1ull));
    if (lane == 0) wsum[wid] = __popcll(mask);
    __syncthreads();
    if (tid == 0) {
      int s = 0;
#pragma unroll
      for (int w = 0; w < 16; w++) { wbase[w] = s; s += wsum[w]; }
      chunkTotal = s;
    }
    __syncthreads();
    if (pred) {
      int pos = total + wbase[wid] + myrank;
      bTok[e * NKA + pos] = a >> 1;
      bW[e * NKA + pos] = tokW[a];
      bFlat[e * NKA + pos] = a;
    }
    total += chunkTotal;
    __syncthreads();
  }
  if (tid == 0) cnt[e] = total;
}

// ---------------- rank within expert + capacity selection ----------------
__global__ void rank_kernel(const int* __restrict__ cnt, int* __restrict__ mrows,
                            const int* __restrict__ bTok, const float* __restrict__ bW,
                            const int* __restrict__ bFlat, int* __restrict__ rowTok,
                            int* __restrict__ tokSlot) {
  int e = blockIdx.x, tid = threadIdx.x;
  int c = cnt[e];
  int m = c < CAP ? c : CAP;
  if (tid == 0) mrows[e] = m;
  if (c <= CAP) {
    for (int p = tid; p < c; p += blockDim.x) {
      int slot = e * CAP + p;
      rowTok[slot] = bTok[e * NKA + p];
      tokSlot[bFlat[e * NKA + p]] = slot;
    }
  } else {
    for (int p = tid; p < c; p += blockDim.x) {
      float wp = bW[e * NKA + p];
      int fp = bFlat[e * NKA + p];
      int rank = 0;
      for (int q = 0; q < c; q++) {
        float wq = bW[e * NKA + q];
        rank += (wq > wp) || (wq == wp && bFlat[e * NKA + q] < fp);
      }
      if (rank < CAP) {
        int slot = e * CAP + rank;
        rowTok[slot] = bTok[e * NKA + p];
        tokSlot[fp] = slot;
      } else {
        tokSlot[fp] = -1;
      }
    }
  }
}

// ---------------- GEMM1: gathered X @ {wg,wu}^T, fused silu*u -> GU fp16 ----------------
// BM=128 x BN=64(g)+64(u) x BK=64; 4 waves 2x2; counted-vmcnt 2-deep pipeline
__global__ __launch_bounds__(256, 2) void gemm1_kernel(
    const f16* __restrict__ Xh, const f16* __restrict__ WGh, const f16* __restrict__ WUh,
    const int* __restrict__ rowTok, const int* __restrict__ mrows, f16* __restrict__ GU) {
  __shared__ __align__(16) f16 As[2][128 * 64];
  __shared__ __align__(16) f16 Bg[2][64 * 64];
  __shared__ __align__(16) f16 Bu[2][64 * 64];

  int bid = ((int)blockIdx.x & 7) * 640 + ((int)blockIdx.x >> 3);  // XCD swizzle (5120 = 8*640)
  int e = bid / (20 * 16);
  int r2 = bid % (20 * 16);
  int rb = r2 / 16, cb = r2 % 16;
  int me = mrows[e];
  if (rb * 128 >= me) return;

  int tid = threadIdx.x;
  int wave = tid >> 6, lane = tid & 63;
  int wr = wave >> 1, wc = wave & 1;

  // A staging: 128x64 = 4 issues of (256 threads x 16B); gather rows via rowTok, pre-swizzled src
  const f16* aSrc[4];
  int aOff[4];
#pragma unroll
  for (int j = 0; j < 4; j++) {
    int o = j * 256 + tid;
    int row = o >> 3, ch = o & 7;
    int rg = rb * 128 + row;
    int tok = (rg < me) ? rowTok[e * CAP + rg] : 0;
    aSrc[j] = Xh + (size_t)tok * HD + ((ch ^ (row & 7)) * 8);
    aOff[j] = o * 8;
  }
  // B staging: 64x64 = 2 issues each
  const f16* gS[2];
  const f16* uS[2];
  int bOff[2];
#pragma unroll
  for (int j = 0; j < 2; j++) {
    int o = j * 256 + tid;
    int row = o >> 3, ch = o & 7;
    size_t w = (size_t)e * ID * HD + (size_t)(cb * 64 + row) * HD + ((ch ^ (row & 7)) * 8);
    gS[j] = WGh + w;
    uS[j] = WUh + w;
    bOff[j] = o * 8;
  }

  auto stage = [&](int buf, int kt) {
    int kh = kt * 64;
#pragma unroll
    for (int j = 0; j < 4; j++) async16(&As[buf][aOff[j]], aSrc[j] + kh);
#pragma unroll
    for (int j = 0; j < 2; j++) async16(&Bg[buf][bOff[j]], gS[j] + kh);
#pragma unroll
    for (int j = 0; j < 2; j++) async16(&Bu[buf][bOff[j]], uS[j] + kh);
  };

  stage(0, 0);
  stage(1, 1);

  f32x4 accg[4][2] = {};
  f32x4 accu[4][2] = {};

  for (int t = 0; t < 16; t++) {
    int cur = t & 1;
    if (t < 15) asm volatile("s_waitcnt vmcnt(8)" ::: "memory");
    else        asm volatile("s_waitcnt vmcnt(0)" ::: "memory");
    __builtin_amdgcn_s_barrier();
    __builtin_amdgcn_sched_barrier(0);

    f16x8 a[4][2], bg[2][2], bu[2][2];
#pragma unroll
    for (int m = 0; m < 4; m++)
#pragma unroll
      for (int kk = 0; kk < 2; kk++) {
        int row = wr * 64 + m * 16 + (lane & 15);
        int c = (kk * 4 + (lane >> 4)) ^ (row & 7);
        a[m][kk] = *(const f16x8*)&As[cur][row * 64 + c * 8];
      }
#pragma unroll
    for (int n = 0; n < 2; n++)
#pragma unroll
      for (int kk = 0; kk < 2; kk++) {
        int row = wc * 32 + n * 16 + (lane & 15);
        int c = (kk * 4 + (lane >> 4)) ^ (row & 7);
        bg[n][kk] = *(const f16x8*)&Bg[cur][row * 64 + c * 8];
        bu[n][kk] = *(const f16x8*)&Bu[cur][row * 64 + c * 8];
      }
    asm volatile("s_waitcnt lgkmcnt(0)" ::: "memory");
    __builtin_amdgcn_sched_barrier(0);
    __builtin_amdgcn_s_barrier();

    if (t + 2 < 16) stage(cur, t + 2);
    __builtin_amdgcn_sched_barrier(0);  // keep stage issues ahead of MFMA cluster

#pragma unroll
    for (int kk = 0; kk < 2; kk++)
#pragma unroll
      for (int m = 0; m < 4; m++)
#pragma unroll
        for (int n = 0; n < 2; n++) {
          accg[m][n] = __builtin_amdgcn_mfma_f32_16x16x32_f16(a[m][kk], bg[n][kk], accg[m][n], 0, 0, 0);
          accu[m][n] = __builtin_amdgcn_mfma_f32_16x16x32_f16(a[m][kk], bu[n][kk], accu[m][n], 0, 0, 0);
        }
  }

  int rbase = e * CAP + rb * 128 + wr * 64;
  int cbase = cb * 64 + wc * 32;
#pragma unroll
  for (int m = 0; m < 4; m++)
#pragma unroll
    for (int n = 0; n < 2; n++)
#pragma unroll
      for (int r = 0; r < 4; r++) {
        int row = rbase + m * 16 + (lane >> 4) * 4 + r;
        int col = cbase + n * 16 + (lane & 15);
        float g = accg[m][n][r];
        float u = accu[m][n][r];
        float s = g / (1.f + __expf(-g));
        GU[(size_t)row * ID + col] = (f16)(s * u);
      }
}

// ---------------- GEMM2: GU @ wd^T -> OE fp16 ----------------
// BM=128 x BN=128 x BK=64; 4 waves 2x2; counted-vmcnt 2-deep pipeline
__global__ __launch_bounds__(256, 2) void gemm2_kernel(
    const f16* __restrict__ GU, const f16* __restrict__ WDh,
    const int* __restrict__ mrows, f16* __restrict__ OE) {
  __shared__ __align__(16) f16 As[2][128 * 64];
  __shared__ __align__(16) f16 Bs[2][128 * 64];

  int bid = ((int)blockIdx.x & 7) * 320 + ((int)blockIdx.x >> 3);  // XCD swizzle (2560 = 8*320)
  int e = bid / (20 * 8);
  int r2 = bid % (20 * 8);
  int rb = r2 / 8, cb = r2 % 8;
  if (rb * 128 >= mrows[e]) return;

  int tid = threadIdx.x;
  int wave = tid >> 6, lane = tid & 63;
  int wr = wave >> 1, wc = wave & 1;

  const f16* aSrc[4];
  const f16* bSrc[4];
  int sOff[4];
#pragma unroll
  for (int j = 0; j < 4; j++) {
    int o = j * 256 + tid;
    int row = o >> 3, ch = o & 7;
    int sw = (ch ^ (row & 7)) * 8;
    aSrc[j] = GU + (size_t)(e * CAP + rb * 128 + row) * ID + sw;
    bSrc[j] = WDh + (size_t)e * HD * ID + (size_t)(cb * 128 + row) * ID + sw;
    sOff[j] = o * 8;
  }

  auto stage = [&](int buf, int kt) {
    int kh = kt * 64;
#pragma unroll
    for (int j = 0; j < 4; j++) async16(&As[buf][sOff[j]], aSrc[j] + kh);
#pragma unroll
    for (int j = 0; j < 4; j++) async16(&Bs[buf][sOff[j]], bSrc[j] + kh);
  };

  stage(0, 0);
  stage(1, 1);

  f32x4 acc[4][4] = {};

  for (int t = 0; t < 16; t++) {
    int cur = t & 1;
    if (t < 15) asm volatile("s_waitcnt vmcnt(8)" ::: "memory");
    else        asm volatile("s_waitcnt vmcnt(0)" ::: "memory");
    __builtin_amdgcn_s_barrier();
    __builtin_amdgcn_sched_barrier(0);

    f16x8 a[4][2], b[4][2];
#pragma unroll
    for (int m = 0; m < 4; m++)
#pragma unroll
      for (int kk = 0; kk < 2; kk++) {
        int row = wr * 64 + m * 16 + (lane & 15);
        int c = (kk * 4 + (lane >> 4)) ^ (row & 7);
        a[m][kk] = *(const f16x8*)&As[cur][row * 64 + c * 8];
      }
#pragma unroll
    for (int n = 0; n < 4; n++)
#pragma unroll
      for (int kk = 0; kk < 2; kk++) {
        int row = wc * 64 + n * 16 + (lane & 15);
        int c = (kk * 4 + (lane >> 4)) ^ (row & 7);
        b[n][kk] = *(const f16x8*)&Bs[cur][row * 64 + c * 8];
      }
    asm volatile("s_waitcnt lgkmcnt(0)" ::: "memory");
    __builtin_amdgcn_sched_barrier(0);
    __builtin_amdgcn_s_barrier();

    if (t + 2 < 16) stage(cur, t + 2);
    __builtin_amdgcn_sched_barrier(0);

#pragma unroll
    for (int kk = 0; kk < 2; kk++)
#pragma unroll
      for (int m = 0; m < 4; m++)
#pragma unroll
        for (int n = 0; n < 4; n++)
          acc[m][n] = __builtin_amdgcn_mfma_f32_16x16x32_f16(a[m][kk], b[n][kk], acc[m][n], 0, 0, 0);
  }

  int rbase = e * CAP + rb * 128 + wr * 64;
  int cbase = cb * 128 + wc * 64;
#pragma unroll
  for (int m = 0; m < 4; m++)
#pragma unroll
    for (int n = 0; n < 4; n++)
#pragma unroll
      for (int r = 0; r < 4; r++) {
        int row = rbase + m * 16 + (lane >> 4) * 4 + r;
        int col = cbase + n * 16 + (lane & 15);
        OE[(size_t)row * HD + col] = (f16)acc[m][n][r];
      }
}

// ---------------- combine: out[t] = sum_k w_k * OE[slot_k] ----------------
__global__ void combine_kernel(const f16* __restrict__ OE, const int* __restrict__ tokSlot,
                               const float* __restrict__ tokW, float* __restrict__ out) {
  int t = blockIdx.x, tid = threadIdx.x;
  int s0 = tokSlot[t * 2], s1 = tokSlot[t * 2 + 1];
  float w0 = tokW[t * 2], w1 = tokW[t * 2 + 1];
  int c = tid * 4;
  float4 o = {0.f, 0.f, 0.f, 0.f};
  if (s0 >= 0) {
    f16x4 v = *(const f16x4*)&OE[(size_t)s0 * HD + c];
    o.x += w0 * (float)v[0]; o.y += w0 * (float)v[1];
    o.z += w0 * (float)v[2]; o.w += w0 * (float)v[3];
  }
  if (s1 >= 0) {
    f16x4 v = *(const f16x4*)&OE[(size_t)s1 * HD + c];
    o.x += w1 * (float)v[0]; o.y += w1 * (float)v[1];
    o.z += w1 * (float)v[2]; o.w += w1 * (float)v[3];
  }
  *(float4*)&out[(size_t)t * HD + c] = o;
  if (t == 0 && tid == 0) out[(size_t)N_TOK * HD] = 0.f;  // aux_loss
}

extern "C" void kernel_launch(void* const* d_in, const int* in_sizes, int n_in,
                              void* d_out, int out_size, void* d_ws, size_t ws_size,
                              hipStream_t stream) {
  (void)in_sizes; (void)n_in; (void)out_size; (void)ws_size;
  const float* x  = (const float*)d_in[0];
  const float* gw = (const float*)d_in[1];
  const float* wg = (const float*)d_in[2];
  const float* wu = (const float*)d_in[3];
  const float* wd = (const float*)d_in[4];
  float* out = (float*)d_out;

  char* ws = (char*)d_ws;
  f16* Xh  = (f16*)ws;                          // 32 MB
  f16* WGh = (f16*)(ws + 33554432ll);           // 32 MB
  f16* WUh = (f16*)(ws + 67108864ll);           // 32 MB
  f16* WDh = (f16*)(ws + 100663296ll);          // 32 MB
  f16* GU  = (f16*)(ws + 134217728ll);          // 80 MB
  f16* OE  = (f16*)ws;                          // aliases Xh/WGh/part-WUh (dead by GEMM2)
  char* rt = ws + 218103808ll;
  int*   cnt     = (int*)rt;                    // 64 B
  int*   mrows   = (int*)(rt + 64);             // 64 B
  int*   rowTok  = (int*)(rt + 128);            // 160 KB
  int*   tokSlot = (int*)(rt + 128 + 163840);   // 128 KB
  float* tokW    = (float*)(rt + 128 + 163840 + 131072);
  char*  rb      = rt + 128 + 163840 + 131072 + 131072;
  int*   bTok  = (int*)rb;                      // 2 MB
  float* bW    = (float*)(rb + 2097152);        // 2 MB
  int*   bFlat = (int*)(rb + 4194304);          // 2 MB
  int*   tokE  = (int*)(rb + 6291456);          // 128 KB

  cvt_kernel<<<4096, 256, 0, stream>>>(x,  Xh,  N_TOK * HD / 4);
  cvt_kernel<<<4096, 256, 0, stream>>>(wg, WGh, NE * ID * HD / 4);
  cvt_kernel<<<4096, 256, 0, stream>>>(wu, WUh, NE * ID * HD / 4);
  cvt_kernel<<<4096, 256, 0, stream>>>(wd, WDh, NE * HD * ID / 4);
  gate_kernel<<<N_TOK / 4, 256, 0, stream>>>(x, gw, tokE, tokW);
  bucket_kernel<<<NE, 1024, 0, stream>>>(tokE, tokW, cnt, bTok, bW, bFlat);
  rank_kernel<<<NE, 256, 0, stream>>>(cnt, mrows, bTok, bW, bFlat, rowTok, tokSlot);
  gemm1_kernel<<<NE * 20 * 16, 256, 0, stream>>>(Xh, WGh, WUh, rowTok, mrows, GU);
  gemm2_kernel<<<NE * 20 * 8, 256, 0, stream>>>(GU, WDh, mrows, OE);
  combine_kernel<<<N_TOK, 256, 0, stream>>>(OE, tokSlot, tokW, out);
}